// Round 2
// baseline (1705.886 us; speedup 1.0000x reference)
//
#include <hip/hip_runtime.h>

// GCN 2-layer: N=100000 nodes, E=3200000 edges, IN=8, HID=64, OUT=1
// Inputs: x[N*8] f32, edge_index[2*E] INT32 (harness converts int64->int32),
//         edge_weight[E] f32, W1[8*64], b1[64], W2[64*1], b2[1]  (all f32)
// Output: out[N] f32.
//
// Algebra: layer1 = (segsum(norm * x[row], col)) @ W1 + b1  (matmul commutes
// with the linear scatter -> aggregate 8-wide instead of 64-wide).
// Layer2: s[n] = relu(h1[n]) @ W2 (scalar), then scalar scatter.

#define GCN_N 100000
#define GCN_E 3200000

// ---- kernel 0: zero the scratch region we accumulate into
__global__ void k_zero(float* __restrict__ p, int n) {
    int i = blockIdx.x * blockDim.x + threadIdx.x;
    int stride = gridDim.x * blockDim.x;
    for (; i < n; i += stride) p[i] = 0.0f;
}

// ---- kernel 1: degree = segment_sum(w, col)  (self-loop +1 folded later)
__global__ void k_deg(const int* __restrict__ col,
                      const float* __restrict__ w,
                      float* __restrict__ deg, int E) {
    int e = blockIdx.x * blockDim.x + threadIdx.x;
    if (e < E) atomicAdd(&deg[col[e]], w[e]);
}

// ---- kernel 2: dinv = rsqrt(deg + 1)   (self-loop weight 1 => deg>0 always)
__global__ void k_dinv(const float* __restrict__ deg,
                       float* __restrict__ dinv, int n) {
    int i = blockIdx.x * blockDim.x + threadIdx.x;
    if (i < n) dinv[i] = rsqrtf(deg[i] + 1.0f);
}

// ---- kernel 3: agg[c][k] += norm * x[r][k], k in [0,8)
__global__ void k_agg(const int* __restrict__ row,
                      const int* __restrict__ col,
                      const float* __restrict__ w,
                      const float* __restrict__ dinv,
                      const float* __restrict__ x,
                      float* __restrict__ agg, int E) {
    int e = blockIdx.x * blockDim.x + threadIdx.x;
    if (e >= E) return;
    int r = row[e];
    int c = col[e];
    float nrm = dinv[r] * w[e] * dinv[c];
    const float4* xr = (const float4*)(x + (size_t)r * 8);
    float4 x0 = xr[0];
    float4 x1 = xr[1];
    float* a = agg + (size_t)c * 8;
    atomicAdd(a + 0, nrm * x0.x);
    atomicAdd(a + 1, nrm * x0.y);
    atomicAdd(a + 2, nrm * x0.z);
    atomicAdd(a + 3, nrm * x0.w);
    atomicAdd(a + 4, nrm * x1.x);
    atomicAdd(a + 5, nrm * x1.y);
    atomicAdd(a + 6, nrm * x1.z);
    atomicAdd(a + 7, nrm * x1.w);
}

// ---- kernel 4: per node: add self-loop, h = a@W1+b1, relu, s = h@W2,
//                out = b2 + dinv^2 * s
__global__ void k_node(const float* __restrict__ agg,
                       const float* __restrict__ x,
                       const float* __restrict__ dinv,
                       const float* __restrict__ W1,
                       const float* __restrict__ b1,
                       const float* __restrict__ W2,
                       const float* __restrict__ b2,
                       float* __restrict__ s,
                       float* __restrict__ out, int n) {
    __shared__ float sW1[8 * 64];
    __shared__ float sb1[64];
    __shared__ float sW2[64];
    int t = threadIdx.x;
    for (int k = t; k < 8 * 64; k += blockDim.x) sW1[k] = W1[k];
    if (t < 64) { sb1[t] = b1[t]; sW2[t] = W2[t]; }
    __syncthreads();
    int i = blockIdx.x * blockDim.x + t;
    if (i >= n) return;
    float di = dinv[i];
    float sl = di * di;               // self-loop norm: dinv*1*dinv
    const float4* ag = (const float4*)(agg + (size_t)i * 8);
    const float4* xr = (const float4*)(x + (size_t)i * 8);
    float4 a0 = ag[0], a1 = ag[1];
    float4 xx0 = xr[0], xx1 = xr[1];
    float a[8];
    a[0] = a0.x + sl * xx0.x;  a[1] = a0.y + sl * xx0.y;
    a[2] = a0.z + sl * xx0.z;  a[3] = a0.w + sl * xx0.w;
    a[4] = a1.x + sl * xx1.x;  a[5] = a1.y + sl * xx1.y;
    a[6] = a1.z + sl * xx1.z;  a[7] = a1.w + sl * xx1.w;
    float acc = 0.0f;
    #pragma unroll
    for (int j = 0; j < 64; j++) {
        float h = sb1[j];
        #pragma unroll
        for (int k = 0; k < 8; k++) h = fmaf(a[k], sW1[k * 64 + j], h);
        acc = fmaf(fmaxf(h, 0.0f), sW2[j], acc);
    }
    s[i] = acc;
    out[i] = b2[0] + sl * acc;        // self-loop of layer 2 + bias
}

// ---- kernel 5: out[c] += norm * s[r]
__global__ void k_out(const int* __restrict__ row,
                      const int* __restrict__ col,
                      const float* __restrict__ w,
                      const float* __restrict__ dinv,
                      const float* __restrict__ s,
                      float* __restrict__ out, int E) {
    int e = blockIdx.x * blockDim.x + threadIdx.x;
    if (e >= E) return;
    int r = row[e];
    int c = col[e];
    float nrm = dinv[r] * w[e] * dinv[c];
    atomicAdd(&out[c], nrm * s[r]);
}

extern "C" void kernel_launch(void* const* d_in, const int* in_sizes, int n_in,
                              void* d_out, int out_size, void* d_ws, size_t ws_size,
                              hipStream_t stream) {
    const float* x  = (const float*)d_in[0];
    const int*   ei = (const int*)d_in[1];    // [2, E] delivered as int32
    const float* w  = (const float*)d_in[2];
    const float* W1 = (const float*)d_in[3];
    const float* b1 = (const float*)d_in[4];
    const float* W2 = (const float*)d_in[5];
    const float* b2 = (const float*)d_in[6];
    float* out = (float*)d_out;

    const int N = GCN_N;
    const int E = GCN_E;
    const int* row = ei;
    const int* col = ei + E;

    float* ws   = (float*)d_ws;
    float* deg  = ws;                 // N
    float* agg  = ws + N;             // 8N
    float* dinv = ws + (size_t)9 * N; // N
    float* s    = ws + (size_t)10 * N;// N

    const int B = 256;
    // zero deg + agg (ws is poisoned with 0xAA before every timed call)
    k_zero<<<512, B, 0, stream>>>(ws, 9 * N);
    k_deg <<<(E + B - 1) / B, B, 0, stream>>>(col, w, deg, E);
    k_dinv<<<(N + B - 1) / B, B, 0, stream>>>(deg, dinv, N);
    k_agg <<<(E + B - 1) / B, B, 0, stream>>>(row, col, w, dinv, x, agg, E);
    k_node<<<(N + B - 1) / B, B, 0, stream>>>(agg, x, dinv, W1, b1, W2, b2, s, out, N);
    k_out <<<(E + B - 1) / B, B, 0, stream>>>(row, col, w, dinv, s, out, E);
}

// Round 3
// 568.432 us; speedup vs baseline: 3.0010x; 3.0010x over previous
//
#include <hip/hip_runtime.h>

// GCN 2-layer: N=100000, E=3200000, IN=8, HID=64, OUT=1.
// Round 3: replace scatter-atomics with per-call CSR (counting sort) + gather.
// Empirical MI355X ceiling ~20G device atomics/s made the 32M-atomic scatter
// version (1706 us) atomic-bound. New design uses 6.4M int atomics total.
//
// ws layout (4B words):
//   cnt[N]      @ 0        edge counts per col (preserved for traversal)
//   ptr[N]      @ N        exclusive prefix sum (CSR row pointers)
//   cur[N]      @ 2N       running fill cursor
//   partial[..] @ 3N       block sums for scan (391 ints)
//   dinv[N]     @ 3N+512   float
//   s[N]        @ 4N+512   float (layer-1 output scalar after @W2)
//   rec[E]      @ 5N+1024  int2 {row, bits(w) -> later bits(norm)}  8B/edge
// total = (5N + 1024 + 2E) * 4 B ~= 27.6 MB

#define GCN_N 100000
#define GCN_E 3200000
#define NBLK  391        // ceil(N/256)

__global__ void k_zero(int* __restrict__ p, int n) {
    int i = blockIdx.x * blockDim.x + threadIdx.x;
    int stride = gridDim.x * blockDim.x;
    for (; i < n; i += stride) p[i] = 0;
}

// histogram of col
__global__ void k_hist(const int* __restrict__ col, int* __restrict__ cnt, int E) {
    int e = blockIdx.x * blockDim.x + threadIdx.x;
    if (e < E) atomicAdd(&cnt[col[e]], 1);
}

// block-local exclusive scan of cnt -> ptr, block totals -> partial
__global__ void k_scan_blk(const int* __restrict__ cnt, int* __restrict__ ptr,
                           int* __restrict__ partial, int n) {
    __shared__ int sm[256];
    int t = threadIdx.x;
    int i = blockIdx.x * 256 + t;
    int v = (i < n) ? cnt[i] : 0;
    sm[t] = v;
    __syncthreads();
    for (int off = 1; off < 256; off <<= 1) {
        int add = (t >= off) ? sm[t - off] : 0;
        __syncthreads();
        sm[t] += add;
        __syncthreads();
    }
    if (i < n) ptr[i] = sm[t] - v;           // exclusive within block
    if (t == 255) partial[blockIdx.x] = sm[t];
}

// single-block exclusive scan of partial[NBLK] in-place
__global__ void k_scan_part(int* __restrict__ partial, int nblk) {
    __shared__ int sm[512];
    int t = threadIdx.x;
    int v = (t < nblk) ? partial[t] : 0;
    sm[t] = v;
    __syncthreads();
    for (int off = 1; off < 512; off <<= 1) {
        int add = (t >= off) ? sm[t - off] : 0;
        __syncthreads();
        sm[t] += add;
        __syncthreads();
    }
    if (t < nblk) partial[t] = sm[t] - v;    // exclusive
}

// add block offsets; init cursor
__global__ void k_scan_add(int* __restrict__ ptr, const int* __restrict__ partial,
                           int* __restrict__ cur, int n) {
    int i = blockIdx.x * 256 + threadIdx.x;
    if (i < n) {
        int p = ptr[i] + partial[blockIdx.x];
        ptr[i] = p;
        cur[i] = p;
    }
}

// scatter edge records into CSR slots
__global__ void k_fill(const int* __restrict__ row, const int* __restrict__ col,
                       const float* __restrict__ w, int* __restrict__ cur,
                       int2* __restrict__ rec, int E) {
    int e = blockIdx.x * blockDim.x + threadIdx.x;
    if (e >= E) return;
    int c = col[e];
    int pos = atomicAdd(&cur[c], 1);
    rec[pos] = make_int2(row[e], __float_as_int(w[e]));
}

// weighted degree per node via gather; dinv = rsqrt(deg + 1)
__global__ void k_deg(const int* __restrict__ ptr, const int* __restrict__ cnt,
                      const int2* __restrict__ rec, float* __restrict__ dinv, int n) {
    int i = blockIdx.x * blockDim.x + threadIdx.x;
    if (i >= n) return;
    int st = ptr[i], en = st + cnt[i];
    float d = 0.0f;
    #pragma unroll 4
    for (int e = st; e < en; e++) d += __int_as_float(rec[e].y);
    dinv[i] = rsqrtf(d + 1.0f);
}

// fused: aggregate 8-wide x over in-edges (+self-loop), h=a@W1+b1, relu,
// s = h@W2. Also overwrites rec[].y with norm for the layer-2 pass.
__global__ void k_aggnode(const int* __restrict__ ptr, const int* __restrict__ cnt,
                          int2* __restrict__ rec,
                          const float* __restrict__ dinv,
                          const float* __restrict__ x,
                          const float* __restrict__ W1,
                          const float* __restrict__ b1,
                          const float* __restrict__ W2,
                          float* __restrict__ s, int n) {
    __shared__ float sW1[8 * 64];
    __shared__ float sb1[64];
    __shared__ float sW2[64];
    int t = threadIdx.x;
    for (int k = t; k < 8 * 64; k += blockDim.x) sW1[k] = W1[k];
    if (t < 64) { sb1[t] = b1[t]; sW2[t] = W2[t]; }
    __syncthreads();
    int i = blockIdx.x * blockDim.x + t;
    if (i >= n) return;
    float di = dinv[i];
    float sl = di * di;
    const float4* xi = (const float4*)(x + (size_t)i * 8);
    float4 x0 = xi[0], x1 = xi[1];
    float a[8];
    a[0] = sl * x0.x; a[1] = sl * x0.y; a[2] = sl * x0.z; a[3] = sl * x0.w;
    a[4] = sl * x1.x; a[5] = sl * x1.y; a[6] = sl * x1.z; a[7] = sl * x1.w;
    int st = ptr[i], en = st + cnt[i];
    #pragma unroll 2
    for (int e = st; e < en; e++) {
        int2 rc = rec[e];
        int r = rc.x;
        float nrm = dinv[r] * __int_as_float(rc.y) * di;
        rec[e].y = __float_as_int(nrm);      // cache norm for layer 2
        const float4* xr = (const float4*)(x + (size_t)r * 8);
        float4 v0 = xr[0], v1 = xr[1];
        a[0] = fmaf(nrm, v0.x, a[0]); a[1] = fmaf(nrm, v0.y, a[1]);
        a[2] = fmaf(nrm, v0.z, a[2]); a[3] = fmaf(nrm, v0.w, a[3]);
        a[4] = fmaf(nrm, v1.x, a[4]); a[5] = fmaf(nrm, v1.y, a[5]);
        a[6] = fmaf(nrm, v1.z, a[6]); a[7] = fmaf(nrm, v1.w, a[7]);
    }
    float acc = 0.0f;
    #pragma unroll
    for (int j = 0; j < 64; j++) {
        float h = sb1[j];
        #pragma unroll
        for (int k = 0; k < 8; k++) h = fmaf(a[k], sW1[k * 64 + j], h);
        acc = fmaf(fmaxf(h, 0.0f), sW2[j], acc);
    }
    s[i] = acc;
}

// layer-2 propagation via gather: out[i] = b2 + sl*s[i] + sum nrm*s[r]
__global__ void k_out2(const int* __restrict__ ptr, const int* __restrict__ cnt,
                       const int2* __restrict__ rec,
                       const float* __restrict__ dinv,
                       const float* __restrict__ s,
                       const float* __restrict__ b2,
                       float* __restrict__ out, int n) {
    int i = blockIdx.x * blockDim.x + threadIdx.x;
    if (i >= n) return;
    float di = dinv[i];
    float acc = b2[0] + di * di * s[i];
    int st = ptr[i], en = st + cnt[i];
    #pragma unroll 4
    for (int e = st; e < en; e++) {
        int2 rc = rec[e];
        acc = fmaf(__int_as_float(rc.y), s[rc.x], acc);
    }
    out[i] = acc;
}

extern "C" void kernel_launch(void* const* d_in, const int* in_sizes, int n_in,
                              void* d_out, int out_size, void* d_ws, size_t ws_size,
                              hipStream_t stream) {
    const float* x  = (const float*)d_in[0];
    const int*   ei = (const int*)d_in[1];    // [2, E] int32
    const float* w  = (const float*)d_in[2];
    const float* W1 = (const float*)d_in[3];
    const float* b1 = (const float*)d_in[4];
    const float* W2 = (const float*)d_in[5];
    const float* b2 = (const float*)d_in[6];
    float* out = (float*)d_out;

    const int N = GCN_N;
    const int E = GCN_E;
    const int* row = ei;
    const int* col = ei + E;

    int*   wsI     = (int*)d_ws;
    int*   cnt     = wsI;
    int*   ptr     = wsI + N;
    int*   cur     = wsI + 2 * N;
    int*   partial = wsI + 3 * N;
    float* dinv    = (float*)(wsI + 3 * N + 512);
    float* s       = (float*)(wsI + 4 * N + 512);
    int2*  rec     = (int2*)(wsI + 5 * N + 1024);

    const int B = 256;
    const int EB = (E + B - 1) / B;

    k_zero     <<<256, B, 0, stream>>>(cnt, N);
    k_hist     <<<EB, B, 0, stream>>>(col, cnt, E);
    k_scan_blk <<<NBLK, B, 0, stream>>>(cnt, ptr, partial, N);
    k_scan_part<<<1, 512, 0, stream>>>(partial, NBLK);
    k_scan_add <<<NBLK, B, 0, stream>>>(ptr, partial, cur, N);
    k_fill     <<<EB, B, 0, stream>>>(row, col, w, cur, rec, E);
    k_deg      <<<NBLK, B, 0, stream>>>(ptr, cnt, rec, dinv, N);
    k_aggnode  <<<NBLK, B, 0, stream>>>(ptr, cnt, rec, dinv, x, W1, b1, W2, s, N);
    k_out2     <<<NBLK, B, 0, stream>>>(ptr, cnt, rec, dinv, s, b2, out, N);
}